// Round 10
// baseline (191.440 us; speedup 1.0000x reference)
//
#include <hip/hip_runtime.h>
#include <math.h>

#define POOLED      7
#define OUTPUT_DIM  21
#define GROUP       7
#define CHANNELS    (OUTPUT_DIM * GROUP * GROUP)   // 1029
#define FH          64
#define FW          64
#define NUM_ROIS    1024
#define SCALE       0.0625f
#define TOTAL       (NUM_ROIS * OUTPUT_DIM * POOLED * POOLED)  // 1,053,696

// Opaque VGPR pin: blocks FMA contraction (hipcc -ffp-contract=fast ignores
// `#pragma clang fp contract(off)`), forces the separately-rounded value.
__device__ __forceinline__ float freeze(float x) {
    __asm__ volatile("" : "+v"(x));
    return x;
}

// One thread per output element (n, d, ph, pw); flat idx == output layout.
//
// ROUND-10 PROBE: bin = roi * RN(1/7) (reciprocal multiply), not roi / 7.
// Rounds 1-9 proved window boundaries are identical across ALL divide-based
// chains (f32-sep barriered, f32-fma, f64, exact-int -> bit-identical absmax
// 0.6213) and that golden ceil-snaps interior ties (r8). Max-statistics of
// 0.6213 imply only tens-to-hundreds of one-pixel flips separate me from the
// golden — too few for corner-rounding or clip-convention differences
// (thousands of flips, absmax 2-4), too many/large for SAT noise (<=1e-2).
// The one untested f32 chain: reciprocal-multiply division (XLA-style
// const-divide canonicalization). Its ~1.3-ulp bin error survives the final
// +start re-snap only at small-start rois at tie sites — exactly the
// tens-to-hundreds flip population observed.
__global__ __launch_bounds__(256)
void psroi_pool_kernel(const float* __restrict__ feat,
                       const float* __restrict__ rois,
                       float* __restrict__ out) {
    int idx = blockIdx.x * blockDim.x + threadIdx.x;
    if (idx >= TOTAL) return;

    int pw = idx % POOLED;
    int ph = (idx / POOLED) % POOLED;
    int d  = (idx / (POOLED * POOLED)) % OUTPUT_DIM;
    int n  = idx / (POOLED * POOLED * OUTPUT_DIM);

    const float* r = rois + n * 5;
    int b = (int)r[0];

    // exact: integers scaled by 1/16
    float start_w = rintf(r[1]) * SCALE;          // np.round = half-to-even
    float start_h = rintf(r[2]) * SCALE;
    float end_w   = rintf(r[3] + 1.0f) * SCALE;
    float end_h   = rintf(r[4] + 1.0f) * SCALE;

    float roi_w = fmaxf(end_w - start_w, 0.1f);   // exact sixteenths
    float roi_h = fmaxf(end_h - start_h, 0.1f);

    // RECIPROCAL MULTIPLY: RN(roi * RN(1/7)) — the probe variable.
    const float inv7 = 1.0f / 7.0f;               // compile-time RN(1/7)
    float bin_h = freeze(roi_h * inv7);
    float bin_w = freeze(roi_w * inv7);

    // separately-rounded mul then add (np semantics), barriered
    float mh0 = freeze((float)ph * bin_h);
    float mh1 = freeze((float)(ph + 1) * bin_h);
    float mw0 = freeze((float)pw * bin_w);
    float mw1 = freeze((float)(pw + 1) * bin_w);

    float hs_f = floorf(mh0 + start_h);
    float he_f = ceilf (mh1 + start_h);
    float ws_f = floorf(mw0 + start_w);
    float we_f = ceilf (mw1 + start_w);

    int hs = (int)fminf(fmaxf(hs_f, 0.0f), (float)FH);
    int he = (int)fminf(fmaxf(he_f, 0.0f), (float)FH);
    int ws = (int)fminf(fmaxf(ws_f, 0.0f), (float)FW);
    int we = (int)fminf(fmaxf(we_f, 0.0f), (float)FW);

    // group indices collapse: gh = ph, gw = pw (POOLED == GROUP == 7)
    int chan = (d * GROUP + ph) * GROUP + pw;
    const float* base = feat + ((size_t)(b * CHANNELS + chan)) * (FH * FW);

    float s = 0.0f;
    for (int h = hs; h < he; ++h) {
        const float* row = base + h * FW;
        for (int w = ws; w < we; ++w) {
            s += row[w];
        }
    }

    int area = (he - hs) * (we - ws);
    out[idx] = (area <= 0) ? 0.0f : s / (float)area;
}

extern "C" void kernel_launch(void* const* d_in, const int* in_sizes, int n_in,
                              void* d_out, int out_size, void* d_ws, size_t ws_size,
                              hipStream_t stream) {
    const float* feat = (const float*)d_in[0];
    const float* rois = (const float*)d_in[1];
    float* out = (float*)d_out;

    int blocks = (TOTAL + 255) / 256;
    psroi_pool_kernel<<<blocks, 256, 0, stream>>>(feat, rois, out);
}

// Round 11
// 157.461 us; speedup vs baseline: 1.2158x; 1.2158x over previous
//
#include <hip/hip_runtime.h>
#include <math.h>

#define POOLED      7
#define OUTPUT_DIM  21
#define GROUP       7
#define CHANNELS    (OUTPUT_DIM * GROUP * GROUP)   // 1029
#define FH          64
#define FW          64
#define NUM_ROIS    1024
#define SCALE       0.0625f

// Opaque VGPR pin: blocks FMA contraction (hipcc -ffp-contract=fast ignores
// `#pragma clang fp contract(off)`). CORRECTNESS-CRITICAL: the golden's
// boundary chain is f32, separately rounded, with bin = roi * RN(1/7)
// (reciprocal multiply) — verified round 10, absmax 3.9e-3. Do not change.
__device__ __forceinline__ float freeze(float x) {
    __asm__ volatile("" : "+v"(x));
    return x;
}

// BIN-MAJOR MAPPING (perf restructure, round 11): one block per channel
// c = (d*7+ph)*7+pw. Channel c is touched ONLY by bin (d,ph,pw), so each
// block owns 4 planes (4 images x 16 KB = 64 KB) exclusively -> every feature
// cache line is fetched by exactly one block; HBM fetch drops from 368 MB
// (17x overfetch: roi-major waves scattered 64 lines/load, zero cross-roi
// L2 reuse) to ~unique (~70 MB). Each thread computes the bin for 4 rois
// (t, t+256, t+512, t+768), unrolled for 4 independent load streams.
// Stores scatter at stride 1029 floats (~25-35 MB at sector granularity) —
// cheap vs the fetch savings.
__global__ __launch_bounds__(256)
void psroi_bin_major(const float* __restrict__ feat,
                     const float* __restrict__ rois,
                     float* __restrict__ out) {
    const int c  = blockIdx.x;            // 0..1028  (== d*49 + ph*7 + pw)
    const int pw = c % 7;
    const int ph = (c / 7) % 7;
    const int t  = threadIdx.x;

    const float* plane_c = feat + (size_t)c * (FH * FW);

#pragma unroll
    for (int k = 0; k < 4; ++k) {
        const int n = t + k * 256;
        const float* r = rois + n * 5;
        const int b = (int)r[0];

        // ---- frozen boundary chain (golden convention, r10-verified) ----
        float start_w = rintf(r[1]) * SCALE;          // np.round = half-even
        float start_h = rintf(r[2]) * SCALE;
        float end_w   = rintf(r[3] + 1.0f) * SCALE;
        float end_h   = rintf(r[4] + 1.0f) * SCALE;

        float roi_w = fmaxf(end_w - start_w, 0.1f);
        float roi_h = fmaxf(end_h - start_h, 0.1f);

        const float inv7 = 1.0f / 7.0f;               // RN(1/7)
        float bin_h = freeze(roi_h * inv7);           // reciprocal multiply
        float bin_w = freeze(roi_w * inv7);

        float mh0 = freeze((float)ph * bin_h);        // separate mul, then add
        float mh1 = freeze((float)(ph + 1) * bin_h);
        float mw0 = freeze((float)pw * bin_w);
        float mw1 = freeze((float)(pw + 1) * bin_w);

        float hs_f = floorf(mh0 + start_h);
        float he_f = ceilf (mh1 + start_h);
        float ws_f = floorf(mw0 + start_w);
        float we_f = ceilf (mw1 + start_w);

        int hs = (int)fminf(fmaxf(hs_f, 0.0f), (float)FH);
        int he = (int)fminf(fmaxf(he_f, 0.0f), (float)FH);
        int ws = (int)fminf(fmaxf(ws_f, 0.0f), (float)FW);
        int we = (int)fminf(fmaxf(we_f, 0.0f), (float)FW);
        // ---- end frozen chain ----

        const float* base = plane_c + (size_t)b * (CHANNELS * FH * FW);

        float s = 0.0f;
        for (int h = hs; h < he; ++h) {
            const float* row = base + h * FW;
            for (int w = ws; w < we; ++w) {
                s += row[w];
            }
        }

        int area = (he - hs) * (we - ws);
        out[(size_t)n * CHANNELS + c] = (area <= 0) ? 0.0f : s / (float)area;
    }
}

extern "C" void kernel_launch(void* const* d_in, const int* in_sizes, int n_in,
                              void* d_out, int out_size, void* d_ws, size_t ws_size,
                              hipStream_t stream) {
    const float* feat = (const float*)d_in[0];
    const float* rois = (const float*)d_in[1];
    float* out = (float*)d_out;

    psroi_bin_major<<<CHANNELS, 256, 0, stream>>>(feat, rois, out);
}